// Round 16
// baseline (157.190 us; speedup 1.0000x reference)
//
#include <hip/hip_runtime.h>
#include <hip/hip_fp16.h>

#define F_IN 128
#define C1 256
#define NEG 0.2f
#define LOG2E 1.4426950408889634f
#define SCAP 32         // slots per shard (2 shards per node; edges only)

typedef _Float16 f16x8 __attribute__((ext_vector_type(8)));
typedef _Float16 f16x4 __attribute__((ext_vector_type(4)));
typedef float f32x4 __attribute__((ext_vector_type(4)));

#define XS_LD 136   // LDS row stride (halfs): staging + half-repack

// ---- K0: build fragment-major weight tables + zero deg2 -------------------
__global__ __launch_bounds__(256) void prep_k(const float* __restrict__ W,
                                              const float* __restrict__ as1,
                                              const float* __restrict__ ad1,
                                              _Float16* __restrict__ FragW,
                                              _Float16* __restrict__ FragAtt,
                                              int* __restrict__ deg2, int N2) {
    int idx = blockIdx.x * 256 + threadIdx.x;
    if (idx < 4096) {
        int lane = idx & 63;
        int ct = (idx >> 6) & 15;
        int ks = idx >> 10;
        int kb = ks * 32 + (lane >> 4) * 8;
        int col = ct * 16 + (lane & 15);
        f16x8 v;
#pragma unroll
        for (int e = 0; e < 8; ++e)
            v[e] = (_Float16)W[(size_t)(kb + e) * C1 + col];
        *(f16x8*)(FragW + (size_t)idx * 8) = v;
    }
    if (idx < 512) {                       // K=256 -> 8 K-steps of 32
        int lane = idx & 63;
        int ks = idx >> 6;                 // 0..7
        int kb = ks * 32 + (lane >> 4) * 8;
        int j = lane & 15;
        f16x8 v;
#pragma unroll
        for (int e = 0; e < 8; ++e) {
            int k = kb + e;                // 0..255
            int hd = k >> 5;
            float val = (j < 8) ? (hd == j ? as1[k] : 0.f)
                                : (hd == (j - 8) ? ad1[k] : 0.f);
            v[e] = (_Float16)(val * LOG2E);
        }
        *(f16x8*)(FragAtt + (size_t)idx * 8) = v;
    }
    for (int i = idx; i < N2; i += gridDim.x * 256) deg2[i] = 0;
}

// ---- K1 fused: group-of-8 interleave of GEMM tiles and XCD-partitioned
//      scatter. group = b>>3; group%9==8 -> GEMM (tile (group/9)*8 + b&7);
//      else scatter chunk (group - group/9), partition b&7. Group base is
//      0 mod 8 so block b -> XCD b%8: scatter keeps its L2-local partition.
__global__ __launch_bounds__(256) void gemm_scat_k(
        const float* __restrict__ x, const _Float16* __restrict__ FragW,
        const _Float16* __restrict__ FragAtt,
        __half* __restrict__ hh, float* __restrict__ asrc, float* __restrict__ adst,
        const int* __restrict__ ei, int* __restrict__ deg2,
        unsigned short* __restrict__ ssrc,
        int N, int E, int nbg, int nch) {
    const int b = blockIdx.x;
    const int group = b >> 3;
    const int sub = b & 7;
    const int gq = group / 9;
    const int gr = group % 9;
    __shared__ _Float16 xs[64 * XS_LD];    // 17.4 KB (all roles reserve it)

    if (gr != 8) {
        // ---------------- scatter role (XCD-partitioned) ----------------
        const int chunk = group - gq;      // skip gemm groups before us
        if (chunk >= nch) return;
        const int part = sub;
        const float pscale = 8.0f / (float)N;
        const int CH = (E + nch - 1) / nch;
        const int beg = chunk * CH;
        const int end = min(beg + CH, E);
        for (int i = beg + threadIdx.x; i < end; i += 256) {
            int d = ei[E + i];
            int p = (int)((float)d * pscale);     // 0..7, same in every block
            if (p != part) continue;
            int s = ei[i];
            int sh = i & 1;
            int slot = atomicAdd(&deg2[d * 2 + sh], 1);
            slot = min(slot, SCAP - 1);           // safety (P ~ 3e-6, clamped)
            ssrc[(d << 6) + sh * SCAP + slot] = (unsigned short)s;
        }
        return;
    }

    // ---------------- GEMM role ----------------
    const int g = gq * 8 + sub;
    if (g >= nbg) return;
    const int t = threadIdx.x;
    const int row0 = g * 64;
    {
        const int r = t >> 2;
        const int c0 = (t & 3) * 32;
        const int grow = row0 + r;
        _Float16* dst = xs + r * XS_LD + c0;
        if (grow < N) {
            const float4* px = (const float4*)(x + (size_t)grow * F_IN + c0);
#pragma unroll
            for (int i = 0; i < 8; ++i) {
                float4 v = px[i];
                f16x4 w;
                w[0] = (_Float16)v.x; w[1] = (_Float16)v.y;
                w[2] = (_Float16)v.z; w[3] = (_Float16)v.w;
                *(f16x4*)(dst + i * 4) = w;
            }
        } else {
            f16x4 z = {0, 0, 0, 0};
#pragma unroll
            for (int i = 0; i < 8; ++i) *(f16x4*)(dst + i * 4) = z;
        }
    }
    __syncthreads();

    const int wid = t >> 6;
    const int lane = t & 63;
    const int l15 = lane & 15;
    const int grp = lane >> 4;
    f32x4 acc[16];
#pragma unroll
    for (int i = 0; i < 16; ++i) acc[i] = (f32x4){0.f, 0.f, 0.f, 0.f};

    const _Float16* arow_p = xs + (wid * 16 + l15) * XS_LD;
    const _Float16* fwl = FragW + (size_t)lane * 8;
#pragma unroll
    for (int ks = 0; ks < 4; ++ks) {
        f16x8 afr = *(const f16x8*)(arow_p + ks * 32 + grp * 8);
#pragma unroll
        for (int ct = 0; ct < 16; ++ct) {
            f16x8 bfr = *(const f16x8*)(fwl + (((ks * 16 + ct) << 9)));
            acc[ct] = __builtin_amdgcn_mfma_f32_16x16x32_f16(afr, bfr, acc[ct], 0, 0, 0);
        }
    }
    __syncthreads();   // xs (x-staging) dead

    // epilogue in two column-halves, reusing xs as h-repack buffer
    f32x4 acca = (f32x4){0.f, 0.f, 0.f, 0.f};
#pragma unroll
    for (int H = 0; H < 2; ++H) {
        {
            _Float16* base = xs + (wid * 16 + grp * 4) * XS_LD + l15;
#pragma unroll
            for (int c8 = 0; c8 < 8; ++c8) {
                int ct = H * 8 + c8;
#pragma unroll
                for (int i = 0; i < 4; ++i)
                    base[i * XS_LD + c8 * 16] = (_Float16)acc[ct][i];
            }
        }
        __syncthreads();
#pragma unroll
        for (int q = 0; q < 4; ++q) {
            int c = q * 256 + t;
            int rl = c >> 4;           // 0..63
            int cc = c & 15;           // chunk within half-row
            int grow = row0 + rl;
            if (grow < N) {
                f16x8 v = *(const f16x8*)(xs + rl * XS_LD + cc * 8);
                *(f16x8*)(hh + (size_t)grow * C1 + H * 128 + cc * 8) = v;
            }
        }
        const _Float16* hrow_p = xs + (wid * 16 + l15) * XS_LD;
#pragma unroll
        for (int ksl = 0; ksl < 4; ++ksl) {
            f16x8 af = *(const f16x8*)(hrow_p + ksl * 32 + grp * 8);
            f16x8 bf = *(const f16x8*)(FragAtt + (size_t)(((H * 4 + ksl) << 6) + lane) * 8);
            acca = __builtin_amdgcn_mfma_f32_16x16x32_f16(af, bf, acca, 0, 0, 0);
        }
        __syncthreads();
    }
#pragma unroll
    for (int i = 0; i < 4; ++i) {
        int grow = row0 + wid * 16 + grp * 4 + i;
        if (grow < N) {
            if (l15 < 8) asrc[grow * 8 + l15] = acca[i];
            else         adst[grow * 8 + (l15 - 8)] = acca[i];
        }
    }
}

// ------- K3: fused layer-1 softmax-aggregate + bias + ReLU + layer-2 -------
// one wave per node; 32 lanes per EDGE (lane l: channels (l&31)*8.., edge
// half=l>>5) -> one f16x8 load per edge-pair, attention math 4x-dup not 8x.
__global__ __launch_bounds__(256) void agg1_k(const __half* __restrict__ hh,
                                              const float* __restrict__ asrc,
                                              const float* __restrict__ adst,
                                              const int* __restrict__ deg2,
                                              const unsigned short* __restrict__ ssrc,
                                              const float* __restrict__ b1,
                                              const float* __restrict__ W2,
                                              const float* __restrict__ as2,
                                              const float* __restrict__ ad2,
                                              float4* __restrict__ tab2, int N) {
    const int lane = threadIdx.x & 63;
    const int n = blockIdx.x * 4 + (threadIdx.x >> 6);
    if (n >= N) return;
    const int half = lane >> 5;
    const int l5 = lane & 31;
    const int hd = l5 >> 2;            // head of this lane's 8 channels
    const int ch0 = l5 * 8;
    const int xoff = l5 * 16;          // byte offset within h row
    const int hoff = hd * 4;           // byte offset within asrc row
    const char* hb = (const char*)hh;
    const char* ab = (const char*)asrc;
    const float adn = adst[n * 8 + hd];   // log2e-scaled

    float ssum = 0.f;
    float4 acc0 = make_float4(0.f, 0.f, 0.f, 0.f);
    float4 acc1 = make_float4(0.f, 0.f, 0.f, 0.f);

#define PAIR(sv) do {                                                         \
    int sA_ = half ? ((int)((sv) >> 16)) : ((int)((sv) & 0xffffu));           \
    f16x8 g_ = *(const f16x8*)(hb + (sA_ << 9) + xoff);                       \
    float a_ = *(const float*)(ab + (sA_ << 5) + hoff) + adn;                 \
    float w_ = exp2f(fmaxf(a_, NEG * a_));                                    \
    ssum += w_;                                                               \
    acc0.x += (float)g_[0] * w_; acc0.y += (float)g_[1] * w_;                 \
    acc0.z += (float)g_[2] * w_; acc0.w += (float)g_[3] * w_;                 \
    acc1.x += (float)g_[4] * w_; acc1.y += (float)g_[5] * w_;                 \
    acc1.z += (float)g_[6] * w_; acc1.w += (float)g_[7] * w_; } while (0)

#define SINGLE(s0) do {                                                       \
    int sA_ = (s0);                                                           \
    f16x8 g_ = *(const f16x8*)(hb + (sA_ << 9) + xoff);                       \
    float a_ = *(const float*)(ab + (sA_ << 5) + hoff) + adn;                 \
    float w_ = exp2f(fmaxf(a_, NEG * a_));                                    \
    if (half) w_ = 0.f;                                                       \
    ssum += w_;                                                               \
    acc0.x += (float)g_[0] * w_; acc0.y += (float)g_[1] * w_;                 \
    acc0.z += (float)g_[2] * w_; acc0.w += (float)g_[3] * w_;                 \
    acc1.x += (float)g_[4] * w_; acc1.y += (float)g_[5] * w_;                 \
    acc1.z += (float)g_[6] * w_; acc1.w += (float)g_[7] * w_; } while (0)

    SINGLE(n);   // self-loop

#pragma unroll
    for (int seg = 0; seg < 2; ++seg) {
        const int dg = min(deg2[n * 2 + seg], SCAP);
        const unsigned short* sp = ssrc + (n << 6) + seg * SCAP;
        int j = 0;
        for (; j + 3 < dg; j += 4) {
            uint2 sv = *(const uint2*)((const unsigned int*)sp + (j >> 1));
            PAIR(sv.x);
            PAIR(sv.y);
        }
        if (j + 1 < dg) {
            unsigned int sv = *((const unsigned int*)sp + (j >> 1));
            PAIR(sv);
            j += 2;
        }
        if (j < dg) SINGLE((int)sp[j]);
    }
#undef PAIR
#undef SINGLE

    // merge halves (each channel's two partials live in lanes l and l+32)
    acc0.x += __shfl_xor(acc0.x, 32); acc0.y += __shfl_xor(acc0.y, 32);
    acc0.z += __shfl_xor(acc0.z, 32); acc0.w += __shfl_xor(acc0.w, 32);
    acc1.x += __shfl_xor(acc1.x, 32); acc1.y += __shfl_xor(acc1.y, 32);
    acc1.z += __shfl_xor(acc1.z, 32); acc1.w += __shfl_xor(acc1.w, 32);
    ssum += __shfl_xor(ssum, 32);

    const float inv = 1.f / ssum;
    float4 bva = *(const float4*)(b1 + ch0);
    float4 bvb = *(const float4*)(b1 + ch0 + 4);
    float o0 = fmaxf(acc0.x * inv + bva.x, 0.f);
    float o1 = fmaxf(acc0.y * inv + bva.y, 0.f);
    float o2 = fmaxf(acc0.z * inv + bva.z, 0.f);
    float o3 = fmaxf(acc0.w * inv + bva.w, 0.f);
    float o4 = fmaxf(acc1.x * inv + bvb.x, 0.f);
    float o5 = fmaxf(acc1.y * inv + bvb.y, 0.f);
    float o6 = fmaxf(acc1.z * inv + bvb.z, 0.f);
    float o7 = fmaxf(acc1.w * inv + bvb.w, 0.f);

    // layer-2 projection: W2 row-major [256][2]; this lane owns rows ch0..+7
    const float4* w2p = (const float4*)(W2 + ch0 * 2);
    float4 q0 = w2p[0], q1 = w2p[1], q2 = w2p[2], q3 = w2p[3];
    float p0 = o0 * q0.x + o1 * q0.z + o2 * q1.x + o3 * q1.z
             + o4 * q2.x + o5 * q2.z + o6 * q3.x + o7 * q3.z;
    float p1 = o0 * q0.y + o1 * q0.w + o2 * q1.y + o3 * q1.w
             + o4 * q2.y + o5 * q2.w + o6 * q3.y + o7 * q3.w;
    if (half) { p0 = 0.f; p1 = 0.f; }   // channels duplicated across halves
#pragma unroll
    for (int off = 1; off < 64; off <<= 1) {
        p0 += __shfl_xor(p0, off);
        p1 += __shfl_xor(p1, off);
    }
    if (lane == 0) {
        float a2s = (p0 * as2[0] + p1 * as2[1]) * LOG2E;
        float a2d = (p0 * ad2[0] + p1 * ad2[1]) * LOG2E;
        tab2[n] = make_float4(p0, p1, a2s, a2d);
    }
}

// ---------------- K4: layer-2 aggregation (8 lanes / node) -----------------
__global__ __launch_bounds__(256) void agg2_k(const int* __restrict__ deg2,
                                              const unsigned short* __restrict__ ssrc,
                                              const float4* __restrict__ tab2,
                                              const float* __restrict__ b2,
                                              float* __restrict__ out, int N) {
    const int t = threadIdx.x;
    const int sub = t & 7;
    const int n = blockIdx.x * 32 + (t >> 3);
    if (n >= N) return;
    const float4 tn = tab2[n];
    const float a2d = tn.w;
    float ssum = 0.f, a0 = 0.f, a1 = 0.f;
    if (sub == 0) {   // self-loop term
        float a = tn.z + a2d;
        a = fmaxf(a, NEG * a);
        float ev = exp2f(a);
        ssum = ev; a0 = tn.x * ev; a1 = tn.y * ev;
    }
#pragma unroll
    for (int seg = 0; seg < 2; ++seg) {
        const int dg = min(deg2[n * 2 + seg], SCAP);
        const unsigned short* sp = ssrc + (n << 6) + seg * SCAP;
        for (int j = sub; j < dg; j += 8) {
            float4 tv = tab2[sp[j]];
            float a = tv.z + a2d;
            a = fmaxf(a, NEG * a);
            float ev = exp2f(a);
            ssum += ev;
            a0 += tv.x * ev;
            a1 += tv.y * ev;
        }
    }
#pragma unroll
    for (int off = 1; off < 8; off <<= 1) {
        ssum += __shfl_xor(ssum, off);
        a0 += __shfl_xor(a0, off);
        a1 += __shfl_xor(a1, off);
    }
    if (sub == 0) {
        float inv = 1.f / ssum;
        out[(size_t)n * 2 + 0] = a0 * inv + b2[0];
        out[(size_t)n * 2 + 1] = a1 * inv + b2[1];
    }
}

extern "C" void kernel_launch(void* const* d_in, const int* in_sizes, int n_in,
                              void* d_out, int out_size, void* d_ws, size_t ws_size,
                              hipStream_t stream) {
    const float* x   = (const float*)d_in[0];
    const int*   ei  = (const int*)d_in[1];
    const float* W1  = (const float*)d_in[2];
    const float* at_s1 = (const float*)d_in[3];
    const float* at_d1 = (const float*)d_in[4];
    const float* b1  = (const float*)d_in[5];
    const float* W2  = (const float*)d_in[6];
    const float* at_s2 = (const float*)d_in[7];
    const float* at_d2 = (const float*)d_in[8];
    const float* b2  = (const float*)d_in[9];
    float* out = (float*)d_out;

    const int N = in_sizes[0] / F_IN;
    const int E = in_sizes[1] / 2;

    char* ws = (char*)d_ws;
    size_t off = 0;
    auto alloc = [&](size_t bytes) -> void* {
        void* p = ws + off;
        off = (off + bytes + 255) & ~(size_t)255;
        return p;
    };
    __half*          hh      = (__half*)alloc((size_t)N * C1 * 2);
    _Float16*        FragW   = (_Float16*)alloc((size_t)4096 * 8 * 2);
    _Float16*        FragAtt = (_Float16*)alloc((size_t)512 * 8 * 2);
    float*           asrc    = (float*)alloc((size_t)N * 8 * 4);
    float*           adst    = (float*)alloc((size_t)N * 8 * 4);
    int*             deg2    = (int*)alloc((size_t)N * 2 * 4);
    unsigned short*  ssrc    = (unsigned short*)alloc((size_t)N * 64 * 2);
    float4*          tab2    = (float4*)alloc((size_t)N * 16);

    prep_k<<<64, 256, 0, stream>>>(W1, at_s1, at_d1, FragW, FragAtt,
                                   deg2, N * 2);

    const int nbg = (N + 63) / 64;            // GEMM tiles
    const int nch = (E + 1023) / 1024;        // scatter chunks
    const int ngg = (nbg + 7) / 8;            // GEMM groups (8 tiles each)
    const int M = (ngg > (nch + 7) / 8) ? ngg : (nch + 7) / 8;
    const int G = M * 9;                      // 8 scat groups : 1 gemm group
    gemm_scat_k<<<G * 8, 256, 0, stream>>>(x, FragW, FragAtt, hh, asrc, adst,
                                           ei, deg2, ssrc, N, E, nbg, nch);
    agg1_k<<<(N + 3) / 4, 256, 0, stream>>>(hh, asrc, adst, deg2, ssrc,
                                            b1, W2, at_s2, at_d2, tab2, N);
    agg2_k<<<(N + 31) / 32, 256, 0, stream>>>(deg2, ssrc, tab2, b2, out, N);
}

// Round 17
// 155.785 us; speedup vs baseline: 1.0090x; 1.0090x over previous
//
#include <hip/hip_runtime.h>
#include <hip/hip_fp16.h>

#define F_IN 128
#define C1 256
#define NEG 0.2f
#define LOG2E 1.4426950408889634f
#define SCAP 32         // slots per shard (2 shards per node; edges only)

typedef _Float16 f16x8 __attribute__((ext_vector_type(8)));
typedef _Float16 f16x4 __attribute__((ext_vector_type(4)));
typedef float f32x4 __attribute__((ext_vector_type(4)));

#define XS_LD 136   // LDS row stride (halfs): staging + half-repack

// ---- K0: build fragment-major weight tables + zero deg2 -------------------
__global__ __launch_bounds__(256) void prep_k(const float* __restrict__ W,
                                              const float* __restrict__ as1,
                                              const float* __restrict__ ad1,
                                              _Float16* __restrict__ FragW,
                                              _Float16* __restrict__ FragAtt,
                                              int* __restrict__ deg2, int N2) {
    int idx = blockIdx.x * 256 + threadIdx.x;
    if (idx < 4096) {
        int lane = idx & 63;
        int ct = (idx >> 6) & 15;
        int ks = idx >> 10;
        int kb = ks * 32 + (lane >> 4) * 8;
        int col = ct * 16 + (lane & 15);
        f16x8 v;
#pragma unroll
        for (int e = 0; e < 8; ++e)
            v[e] = (_Float16)W[(size_t)(kb + e) * C1 + col];
        *(f16x8*)(FragW + (size_t)idx * 8) = v;
    }
    if (idx < 512) {                       // K=256 -> 8 K-steps of 32
        int lane = idx & 63;
        int ks = idx >> 6;                 // 0..7
        int kb = ks * 32 + (lane >> 4) * 8;
        int j = lane & 15;
        f16x8 v;
#pragma unroll
        for (int e = 0; e < 8; ++e) {
            int k = kb + e;                // 0..255
            int hd = k >> 5;
            float val = (j < 8) ? (hd == j ? as1[k] : 0.f)
                                : (hd == (j - 8) ? ad1[k] : 0.f);
            v[e] = (_Float16)(val * LOG2E);
        }
        *(f16x8*)(FragAtt + (size_t)idx * 8) = v;
    }
    for (int i = idx; i < N2; i += gridDim.x * 256) deg2[i] = 0;
}

// ---- K1: gemm x@W1 -> h fp16 + att coefs (log2e-scaled); lean 17.4 KB LDS -
__global__ __launch_bounds__(256) void gemm_att_k(
        const float* __restrict__ x, const _Float16* __restrict__ FragW,
        const _Float16* __restrict__ FragAtt,
        __half* __restrict__ hh, float* __restrict__ asrc, float* __restrict__ adst,
        int N) {
    __shared__ _Float16 xs[64 * XS_LD];    // 17.4 KB
    const int t = threadIdx.x;
    const int row0 = blockIdx.x * 64;
    {
        const int r = t >> 2;
        const int c0 = (t & 3) * 32;
        const int gr = row0 + r;
        _Float16* dst = xs + r * XS_LD + c0;
        if (gr < N) {
            const float4* px = (const float4*)(x + (size_t)gr * F_IN + c0);
#pragma unroll
            for (int i = 0; i < 8; ++i) {
                float4 v = px[i];
                f16x4 w;
                w[0] = (_Float16)v.x; w[1] = (_Float16)v.y;
                w[2] = (_Float16)v.z; w[3] = (_Float16)v.w;
                *(f16x4*)(dst + i * 4) = w;
            }
        } else {
            f16x4 z = {0, 0, 0, 0};
#pragma unroll
            for (int i = 0; i < 8; ++i) *(f16x4*)(dst + i * 4) = z;
        }
    }
    __syncthreads();

    const int wid = t >> 6;
    const int lane = t & 63;
    const int l15 = lane & 15;
    const int grp = lane >> 4;
    f32x4 acc[16];
#pragma unroll
    for (int i = 0; i < 16; ++i) acc[i] = (f32x4){0.f, 0.f, 0.f, 0.f};

    const _Float16* arow_p = xs + (wid * 16 + l15) * XS_LD;
    const _Float16* fwl = FragW + (size_t)lane * 8;
#pragma unroll
    for (int ks = 0; ks < 4; ++ks) {
        f16x8 afr = *(const f16x8*)(arow_p + ks * 32 + grp * 8);
#pragma unroll
        for (int ct = 0; ct < 16; ++ct) {
            f16x8 bfr = *(const f16x8*)(fwl + (((ks * 16 + ct) << 9)));
            acc[ct] = __builtin_amdgcn_mfma_f32_16x16x32_f16(afr, bfr, acc[ct], 0, 0, 0);
        }
    }
    __syncthreads();   // xs (x-staging) dead

    // epilogue in two column-halves, reusing xs as h-repack buffer
    f32x4 acca = (f32x4){0.f, 0.f, 0.f, 0.f};
#pragma unroll
    for (int H = 0; H < 2; ++H) {
        {
            _Float16* base = xs + (wid * 16 + grp * 4) * XS_LD + l15;
#pragma unroll
            for (int c8 = 0; c8 < 8; ++c8) {
                int ct = H * 8 + c8;
#pragma unroll
                for (int i = 0; i < 4; ++i)
                    base[i * XS_LD + c8 * 16] = (_Float16)acc[ct][i];
            }
        }
        __syncthreads();
#pragma unroll
        for (int q = 0; q < 4; ++q) {
            int c = q * 256 + t;
            int rl = c >> 4;           // 0..63
            int cc = c & 15;           // chunk within half-row
            int gr = row0 + rl;
            if (gr < N) {
                f16x8 v = *(const f16x8*)(xs + rl * XS_LD + cc * 8);
                *(f16x8*)(hh + (size_t)gr * C1 + H * 128 + cc * 8) = v;
            }
        }
        const _Float16* hrow_p = xs + (wid * 16 + l15) * XS_LD;
#pragma unroll
        for (int ksl = 0; ksl < 4; ++ksl) {
            f16x8 af = *(const f16x8*)(hrow_p + ksl * 32 + grp * 8);
            f16x8 bf = *(const f16x8*)(FragAtt + (size_t)(((H * 4 + ksl) << 6) + lane) * 8);
            acca = __builtin_amdgcn_mfma_f32_16x16x32_f16(af, bf, acca, 0, 0, 0);
        }
        __syncthreads();
    }
#pragma unroll
    for (int i = 0; i < 4; ++i) {
        int gr = row0 + wid * 16 + grp * 4 + i;
        if (gr < N) {
            if (l15 < 8) asrc[gr * 8 + l15] = acca[i];
            else         adst[gr * 8 + (l15 - 8)] = acca[i];
        }
    }
}

// ---- K2: XCD-partitioned bucket-scatter -----------------------------------
// block b: chunk = b>>3, part = b&7. Only edges with part(dst)==part are
// scattered -> all stores/atomics for a node come from one XCD (b%8 round-
// robin mapping); its 800KB ssrc partition stays L2-resident (no RMW thrash).
__global__ __launch_bounds__(256) void scat_k(const int* __restrict__ ei,
                                              int* __restrict__ deg2,
                                              unsigned short* __restrict__ ssrc,
                                              int E, int N, int nch) {
    const int part = blockIdx.x & 7;
    const int chunk = blockIdx.x >> 3;
    const float pscale = 8.0f / (float)N;     // deterministic per-edge part()
    const int CH = (E + nch - 1) / nch;
    const int b = chunk * CH;
    const int e = min(b + CH, E);
    for (int i = b + threadIdx.x; i < e; i += 256) {
        int d = ei[E + i];
        int p = (int)((float)d * pscale);     // 0..7, same in every block
        if (p != part) continue;
        int s = ei[i];
        int sh = i & 1;
        int slot = atomicAdd(&deg2[d * 2 + sh], 1);
        slot = min(slot, SCAP - 1);           // memory safety (P ~ 3e-6, clamped)
        ssrc[(d << 6) + sh * SCAP + slot] = (unsigned short)s;
    }
}

// ------- K3: fused layer-1 softmax-aggregate + bias + ReLU + layer-2 -------
// one wave per node; 32 lanes per EDGE (lane l: channels (l&31)*8.., edge
// half=l>>5) -> one f16x8 load per edge-pair, attention math 4x-dup not 8x.
__global__ __launch_bounds__(256) void agg1_k(const __half* __restrict__ hh,
                                              const float* __restrict__ asrc,
                                              const float* __restrict__ adst,
                                              const int* __restrict__ deg2,
                                              const unsigned short* __restrict__ ssrc,
                                              const float* __restrict__ b1,
                                              const float* __restrict__ W2,
                                              const float* __restrict__ as2,
                                              const float* __restrict__ ad2,
                                              float4* __restrict__ tab2, int N) {
    const int lane = threadIdx.x & 63;
    const int n = blockIdx.x * 4 + (threadIdx.x >> 6);
    if (n >= N) return;
    const int half = lane >> 5;
    const int l5 = lane & 31;
    const int hd = l5 >> 2;            // head of this lane's 8 channels
    const int ch0 = l5 * 8;
    const int xoff = l5 * 16;          // byte offset within h row
    const int hoff = hd * 4;           // byte offset within asrc row
    const char* hb = (const char*)hh;
    const char* ab = (const char*)asrc;
    const float adn = adst[n * 8 + hd];   // log2e-scaled

    float ssum = 0.f;
    float4 acc0 = make_float4(0.f, 0.f, 0.f, 0.f);
    float4 acc1 = make_float4(0.f, 0.f, 0.f, 0.f);

#define PAIR(sv) do {                                                         \
    int sA_ = half ? ((int)((sv) >> 16)) : ((int)((sv) & 0xffffu));           \
    f16x8 g_ = *(const f16x8*)(hb + (sA_ << 9) + xoff);                       \
    float a_ = *(const float*)(ab + (sA_ << 5) + hoff) + adn;                 \
    float w_ = exp2f(fmaxf(a_, NEG * a_));                                    \
    ssum += w_;                                                               \
    acc0.x += (float)g_[0] * w_; acc0.y += (float)g_[1] * w_;                 \
    acc0.z += (float)g_[2] * w_; acc0.w += (float)g_[3] * w_;                 \
    acc1.x += (float)g_[4] * w_; acc1.y += (float)g_[5] * w_;                 \
    acc1.z += (float)g_[6] * w_; acc1.w += (float)g_[7] * w_; } while (0)

#define SINGLE(s0) do {                                                       \
    int sA_ = (s0);                                                           \
    f16x8 g_ = *(const f16x8*)(hb + (sA_ << 9) + xoff);                       \
    float a_ = *(const float*)(ab + (sA_ << 5) + hoff) + adn;                 \
    float w_ = exp2f(fmaxf(a_, NEG * a_));                                    \
    if (half) w_ = 0.f;                                                       \
    ssum += w_;                                                               \
    acc0.x += (float)g_[0] * w_; acc0.y += (float)g_[1] * w_;                 \
    acc0.z += (float)g_[2] * w_; acc0.w += (float)g_[3] * w_;                 \
    acc1.x += (float)g_[4] * w_; acc1.y += (float)g_[5] * w_;                 \
    acc1.z += (float)g_[6] * w_; acc1.w += (float)g_[7] * w_; } while (0)

    SINGLE(n);   // self-loop

#pragma unroll
    for (int seg = 0; seg < 2; ++seg) {
        const int dg = min(deg2[n * 2 + seg], SCAP);
        const unsigned short* sp = ssrc + (n << 6) + seg * SCAP;
        int j = 0;
        for (; j + 3 < dg; j += 4) {
            uint2 sv = *(const uint2*)((const unsigned int*)sp + (j >> 1));
            PAIR(sv.x);
            PAIR(sv.y);
        }
        if (j + 1 < dg) {
            unsigned int sv = *((const unsigned int*)sp + (j >> 1));
            PAIR(sv);
            j += 2;
        }
        if (j < dg) SINGLE((int)sp[j]);
    }
#undef PAIR
#undef SINGLE

    // merge halves (each channel's two partials live in lanes l and l+32)
    acc0.x += __shfl_xor(acc0.x, 32); acc0.y += __shfl_xor(acc0.y, 32);
    acc0.z += __shfl_xor(acc0.z, 32); acc0.w += __shfl_xor(acc0.w, 32);
    acc1.x += __shfl_xor(acc1.x, 32); acc1.y += __shfl_xor(acc1.y, 32);
    acc1.z += __shfl_xor(acc1.z, 32); acc1.w += __shfl_xor(acc1.w, 32);
    ssum += __shfl_xor(ssum, 32);

    const float inv = 1.f / ssum;
    float4 bva = *(const float4*)(b1 + ch0);
    float4 bvb = *(const float4*)(b1 + ch0 + 4);
    float o0 = fmaxf(acc0.x * inv + bva.x, 0.f);
    float o1 = fmaxf(acc0.y * inv + bva.y, 0.f);
    float o2 = fmaxf(acc0.z * inv + bva.z, 0.f);
    float o3 = fmaxf(acc0.w * inv + bva.w, 0.f);
    float o4 = fmaxf(acc1.x * inv + bvb.x, 0.f);
    float o5 = fmaxf(acc1.y * inv + bvb.y, 0.f);
    float o6 = fmaxf(acc1.z * inv + bvb.z, 0.f);
    float o7 = fmaxf(acc1.w * inv + bvb.w, 0.f);

    // layer-2 projection: W2 row-major [256][2]; this lane owns rows ch0..+7
    const float4* w2p = (const float4*)(W2 + ch0 * 2);
    float4 q0 = w2p[0], q1 = w2p[1], q2 = w2p[2], q3 = w2p[3];
    float p0 = o0 * q0.x + o1 * q0.z + o2 * q1.x + o3 * q1.z
             + o4 * q2.x + o5 * q2.z + o6 * q3.x + o7 * q3.z;
    float p1 = o0 * q0.y + o1 * q0.w + o2 * q1.y + o3 * q1.w
             + o4 * q2.y + o5 * q2.w + o6 * q3.y + o7 * q3.w;
    if (half) { p0 = 0.f; p1 = 0.f; }   // channels duplicated across halves
#pragma unroll
    for (int off = 1; off < 64; off <<= 1) {
        p0 += __shfl_xor(p0, off);
        p1 += __shfl_xor(p1, off);
    }
    if (lane == 0) {
        float a2s = (p0 * as2[0] + p1 * as2[1]) * LOG2E;
        float a2d = (p0 * ad2[0] + p1 * ad2[1]) * LOG2E;
        tab2[n] = make_float4(p0, p1, a2s, a2d);
    }
}

// ---------------- K4: layer-2 aggregation (8 lanes / node) -----------------
__global__ __launch_bounds__(256) void agg2_k(const int* __restrict__ deg2,
                                              const unsigned short* __restrict__ ssrc,
                                              const float4* __restrict__ tab2,
                                              const float* __restrict__ b2,
                                              float* __restrict__ out, int N) {
    const int t = threadIdx.x;
    const int sub = t & 7;
    const int n = blockIdx.x * 32 + (t >> 3);
    if (n >= N) return;
    const float4 tn = tab2[n];
    const float a2d = tn.w;
    float ssum = 0.f, a0 = 0.f, a1 = 0.f;
    if (sub == 0) {   // self-loop term
        float a = tn.z + a2d;
        a = fmaxf(a, NEG * a);
        float ev = exp2f(a);
        ssum = ev; a0 = tn.x * ev; a1 = tn.y * ev;
    }
#pragma unroll
    for (int seg = 0; seg < 2; ++seg) {
        const int dg = min(deg2[n * 2 + seg], SCAP);
        const unsigned short* sp = ssrc + (n << 6) + seg * SCAP;
        for (int j = sub; j < dg; j += 8) {
            float4 tv = tab2[sp[j]];
            float a = tv.z + a2d;
            a = fmaxf(a, NEG * a);
            float ev = exp2f(a);
            ssum += ev;
            a0 += tv.x * ev;
            a1 += tv.y * ev;
        }
    }
#pragma unroll
    for (int off = 1; off < 8; off <<= 1) {
        ssum += __shfl_xor(ssum, off);
        a0 += __shfl_xor(a0, off);
        a1 += __shfl_xor(a1, off);
    }
    if (sub == 0) {
        float inv = 1.f / ssum;
        out[(size_t)n * 2 + 0] = a0 * inv + b2[0];
        out[(size_t)n * 2 + 1] = a1 * inv + b2[1];
    }
}

extern "C" void kernel_launch(void* const* d_in, const int* in_sizes, int n_in,
                              void* d_out, int out_size, void* d_ws, size_t ws_size,
                              hipStream_t stream) {
    const float* x   = (const float*)d_in[0];
    const int*   ei  = (const int*)d_in[1];
    const float* W1  = (const float*)d_in[2];
    const float* at_s1 = (const float*)d_in[3];
    const float* at_d1 = (const float*)d_in[4];
    const float* b1  = (const float*)d_in[5];
    const float* W2  = (const float*)d_in[6];
    const float* at_s2 = (const float*)d_in[7];
    const float* at_d2 = (const float*)d_in[8];
    const float* b2  = (const float*)d_in[9];
    float* out = (float*)d_out;

    const int N = in_sizes[0] / F_IN;
    const int E = in_sizes[1] / 2;

    char* ws = (char*)d_ws;
    size_t off = 0;
    auto alloc = [&](size_t bytes) -> void* {
        void* p = ws + off;
        off = (off + bytes + 255) & ~(size_t)255;
        return p;
    };
    __half*          hh      = (__half*)alloc((size_t)N * C1 * 2);
    _Float16*        FragW   = (_Float16*)alloc((size_t)4096 * 8 * 2);
    _Float16*        FragAtt = (_Float16*)alloc((size_t)512 * 8 * 2);
    float*           asrc    = (float*)alloc((size_t)N * 8 * 4);
    float*           adst    = (float*)alloc((size_t)N * 8 * 4);
    int*             deg2    = (int*)alloc((size_t)N * 2 * 4);
    unsigned short*  ssrc    = (unsigned short*)alloc((size_t)N * 64 * 2);
    float4*          tab2    = (float4*)alloc((size_t)N * 16);

    prep_k<<<64, 256, 0, stream>>>(W1, at_s1, at_d1, FragW, FragAtt,
                                   deg2, N * 2);
    const int nbg = (N + 63) / 64;
    gemm_att_k<<<nbg, 256, 0, stream>>>(x, FragW, FragAtt, hh, asrc, adst, N);
    const int nch = (E + 1023) / 1024;            // edge chunks
    scat_k<<<nch * 8, 256, 0, stream>>>(ei, deg2, ssrc, E, N, nch);
    agg1_k<<<(N + 3) / 4, 256, 0, stream>>>(hh, asrc, adst, deg2, ssrc,
                                            b1, W2, at_s2, at_d2, tab2, N);
    agg2_k<<<(N + 31) / 32, 256, 0, stream>>>(deg2, ssrc, tab2, b2, out, N);
}